// Round 6
// baseline (110.938 us; speedup 1.0000x reference)
//
#include <hip/hip_runtime.h>
#include <math.h>

typedef unsigned int uint;
typedef unsigned short ushort;

using short8 = __attribute__((ext_vector_type(8))) short;
using f32x4  = __attribute__((ext_vector_type(4))) float;

#define BT      65536
#define HID     512
#define IN_DIM  594
#define TRUNK   256
#define BINS    20
#define NCOMBO  320

#define WT_P_SZ (19*16*64*8)
#define RP_SZ   (16*64*8)
#define WA_P_SZ (8*20*64*8)

__device__ inline ushort f2bf(float f) {
    uint u = __float_as_uint(f);
    return (ushort)((u + 0x7fffu + ((u >> 16) & 1u)) >> 16);   // RNE
}

// ---------------------------------------------------------------------------
// Pack weights to bf16 MFMA B-fragment layout (verified R2-R5):
//   frag elem j, lane l, frag (kk,n): B[k][col], k=kk*32+(l>>4)*8+j, col=n*16+(l&15)
// ---------------------------------------------------------------------------
__global__ __launch_bounds__(64) void pack_all(
    const float* __restrict__ trunk_w, const float* __restrict__ router_w,
    const float* __restrict__ inst_base_w, const float* __restrict__ inst_base_b,
    const float* __restrict__ group_base_w, const float* __restrict__ group_base_b,
    const float* __restrict__ inst_exp_w, const float* __restrict__ inst_exp_b,
    const float* __restrict__ group_exp_w, const float* __restrict__ group_exp_b,
    ushort* __restrict__ WtP, ushort* __restrict__ RP,
    ushort* __restrict__ WaP, float* __restrict__ wbias)
{
    const int b = blockIdx.x, l = threadIdx.x;
    const int lr = l & 15, lg = l >> 4;
    if (b < 304) {                      // trunk: kk 0..18, n 0..15
        int kk = b >> 4, n = b & 15;
        int col = n * 16 + lr;
        ushort* dst = WtP + ((size_t)(kk * 16 + n) * 64 + l) * 8;
        #pragma unroll
        for (int j = 0; j < 8; ++j) {
            int k = kk * 32 + lg * 8 + j;
            dst[j] = (k < IN_DIM) ? f2bf(trunk_w[k * TRUNK + col]) : (ushort)0;
        }
    } else if (b < 320) {               // router: kk 0..15
        int kk = b - 304;
        ushort* dst = RP + ((size_t)(kk * 64 + l)) * 8;
        #pragma unroll
        for (int j = 0; j < 8; ++j) {
            int k = kk * 32 + lg * 8 + j;
            dst[j] = (lr < 7) ? f2bf(router_w[k * 7 + lr]) : (ushort)0;
        }
    } else if (b < 480) {               // heads: kk 0..7, n 0..19
        int b2 = b - 320, kk = b2 / 20, n = b2 % 20;
        int combo = n * 16 + lr;
        int h = combo / 160, rem = combo % 160, kb = rem >> 3, p = rem & 7;
        const float* bw = h ? group_base_w : inst_base_w;
        const float* ew = h ? group_exp_w  : inst_exp_w;
        ushort* dst = WaP + ((size_t)(kk * 20 + n) * 64 + l) * 8;
        #pragma unroll
        for (int j = 0; j < 8; ++j) {
            int k = kk * 32 + lg * 8 + j;
            float v = (p == 0) ? bw[k * BINS + kb]
                               : ew[((p - 1) * TRUNK + k) * BINS + kb];
            dst[j] = f2bf(v);
        }
    } else {                            // bias[320]
        for (int c = l; c < NCOMBO; c += 64) {
            int h = c / 160, rem = c % 160, kb = rem >> 3, p = rem & 7;
            const float* bb = h ? group_base_b : inst_base_b;
            const float* eb = h ? group_exp_b  : inst_exp_b;
            wbias[c] = (p == 0) ? bb[kb] : eb[(p - 1) * BINS + kb];
        }
    }
}

// ---------------------------------------------------------------------------
// Fused main: 64 tokens/block, 4 waves, 1024 blocks -> 3 blocks/CU (12 waves).
// Phase A: N-split trunk (wave w: N-frags 4w..4w+3, all 4 M-frags);
//          x dbuf-staged in A-frag layout (4KB/kk); router per-wave all rows.
// Phase C: N-split heads (wave w: N-frags 5w..5w+4, all rows) -> head weights
//          read once per block.
// LDS: zs[64][256] bf16 swizzled (32 KB), xs[2] overlaps first 8 KB.
// ---------------------------------------------------------------------------
__global__ __launch_bounds__(256, 3) void fused_mfma(
    const float* __restrict__ h_t, const float* __restrict__ a_t,
    const float* __restrict__ d_t, const float* __restrict__ age,
    const float* __restrict__ trunk_b, const float* __restrict__ router_b,
    const ushort* __restrict__ WtP, const ushort* __restrict__ RP,
    const ushort* __restrict__ WaP, const float* __restrict__ wbias,
    float* __restrict__ out)
{
    __shared__ alignas(16) ushort zs[16384];   // 32 KB; first 4096 ushorts = xs[2]

    const int tid = threadIdx.x;
    const int l = tid & 63, w = tid >> 6;
    const int lr = l & 15, lg = l >> 4;
    const int block0 = blockIdx.x * 64;

    // staging mapping: thread -> (row 0..63, col-quarter 0..3 of 32-col chunk)
    const int srow = tid >> 2;
    const int sq   = tid & 3;
    const size_t stok = block0 + srow;

    ushort* xs = zs;                 // xs[buf][frag mm 0..3][lane*8], buf stride 2048

    f32x4 acc[4][4];                 // [M-frag][N-frag] 64 VGPRs
    f32x4 accr[4];                   // router, all 4 M-frags (redundant per wave)
    #pragma unroll
    for (int mm = 0; mm < 4; ++mm) {
        accr[mm] = (f32x4){0.f,0.f,0.f,0.f};
        #pragma unroll
        for (int nn = 0; nn < 4; ++nn) acc[mm][nn] = (f32x4){0.f,0.f,0.f,0.f};
    }

    auto stage_load = [&](int kk, float4 ld[2]) {
        if (kk < 16) {
            const float4* p = (const float4*)(h_t + stok * HID + kk * 32 + sq * 8);
            ld[0] = p[0]; ld[1] = p[1];
        } else if (kk < 18) {
            const float4* p = (const float4*)(a_t + stok * 64 + (kk - 16) * 32 + sq * 8);
            ld[0] = p[0]; ld[1] = p[1];
        } else {
            float* f = (float*)ld;
            #pragma unroll
            for (int j = 0; j < 8; ++j) {
                int c = 576 + sq * 8 + j;
                float v;
                if (c < 578)      v = d_t[stok * 2 + (c - 576)];
                else if (c < 594) v = age[stok * 16 + (c - 578)];
                else              v = 0.f;
                f[j] = v;
            }
        }
    };
    // A-frag layout write: value(row, k): frag mm=row>>4, lane=(row&15)+(k>>3)*16,
    // elem j=k&7. Thread's 8 values (k=sq*8..+7) -> one short8 at one lane.
    auto stage_write = [&](int buf, float4 ld[2]) {
        const float* f = (const float*)ld;
        short8 v;
        #pragma unroll
        for (int j = 0; j < 8; ++j) v[j] = (short)f2bf(f[j]);
        *(short8*)(xs + buf * 2048 + ((srow >> 4) * 64 + (srow & 15) + sq * 16) * 8) = v;
    };

    // ---- phase A: trunk (K=608, N-split) + router (K=512, all M-frags) ----
    {
        float4 ld[2];
        stage_load(0, ld);
        stage_write(0, ld);
        __syncthreads();
        int cur = 0;
        #pragma unroll 1
        for (int kk = 0; kk < 19; ++kk) {
            float4 nld[2];
            if (kk < 18) stage_load(kk + 1, nld);    // issue early

            const ushort* xb = xs + cur * 2048;
            short8 a0 = *(const short8*)(xb + (0 * 64 + l) * 8);
            short8 a1 = *(const short8*)(xb + (1 * 64 + l) * 8);
            short8 a2 = *(const short8*)(xb + (2 * 64 + l) * 8);
            short8 a3 = *(const short8*)(xb + (3 * 64 + l) * 8);

            const ushort* wp = WtP + ((size_t)kk * 16 + w * 4) * 512;
            short8 bq[4];
            #pragma unroll
            for (int nn = 0; nn < 4; ++nn)
                bq[nn] = *(const short8*)(wp + (size_t)nn * 512 + l * 8);

            if (kk < 16) {
                short8 rb = *(const short8*)(RP + (size_t)kk * 512 + l * 8);
                accr[0] = __builtin_amdgcn_mfma_f32_16x16x32_bf16(a0, rb, accr[0],0,0,0);
                accr[1] = __builtin_amdgcn_mfma_f32_16x16x32_bf16(a1, rb, accr[1],0,0,0);
                accr[2] = __builtin_amdgcn_mfma_f32_16x16x32_bf16(a2, rb, accr[2],0,0,0);
                accr[3] = __builtin_amdgcn_mfma_f32_16x16x32_bf16(a3, rb, accr[3],0,0,0);
            }
            #pragma unroll
            for (int nn = 0; nn < 4; ++nn) {
                acc[0][nn] = __builtin_amdgcn_mfma_f32_16x16x32_bf16(a0, bq[nn], acc[0][nn],0,0,0);
                acc[1][nn] = __builtin_amdgcn_mfma_f32_16x16x32_bf16(a1, bq[nn], acc[1][nn],0,0,0);
                acc[2][nn] = __builtin_amdgcn_mfma_f32_16x16x32_bf16(a2, bq[nn], acc[2][nn],0,0,0);
                acc[3][nn] = __builtin_amdgcn_mfma_f32_16x16x32_bf16(a3, bq[nn], acc[3][nn],0,0,0);
            }

            if (kk < 18) stage_write(cur ^ 1, nld);  // write late
            __syncthreads();
            cur ^= 1;
        }
    }

    // ---- router softmax in registers (all 64 rows, per wave) --------------
    float pwv[4][4];
    {
        const float rb_l = (lr < 7) ? router_b[lr] : 0.f;
        #pragma unroll
        for (int mm = 0; mm < 4; ++mm)
        #pragma unroll
        for (int r = 0; r < 4; ++r) {
            float x = (lr < 7) ? (accr[mm][r] + rb_l) : -3.0e38f;
            float mx = x;
            mx = fmaxf(mx, __shfl_xor(mx, 1));
            mx = fmaxf(mx, __shfl_xor(mx, 2));
            mx = fmaxf(mx, __shfl_xor(mx, 4));
            mx = fmaxf(mx, __shfl_xor(mx, 8));
            float e = expf(x - mx);
            float s = e;
            s += __shfl_xor(s, 1);
            s += __shfl_xor(s, 2);
            s += __shfl_xor(s, 4);
            s += __shfl_xor(s, 8);
            pwv[mm][r] = e / s;
        }
    }

    // ---- epilogue: bias + exact GELU -> swizzled bf16 zs ------------------
    // wave w writes cols w*64..+63 for all 64 rows (xs region dead now)
    {
        char* zb = (char*)zs;
        #pragma unroll
        for (int nn = 0; nn < 4; ++nn) {
            int colbase = (w * 4 + nn) * 16 + lr;
            float tb = trunk_b[colbase];
            #pragma unroll
            for (int mm = 0; mm < 4; ++mm)
            #pragma unroll
            for (int r = 0; r < 4; ++r) {
                float v = acc[mm][nn][r] + tb;
                v = 0.5f * v * (1.f + erff(v * 0.70710678118654752f));
                int row  = mm * 16 + lg * 4 + r;
                int slot = (colbase >> 3) ^ (row & 7);
                *(ushort*)(zb + row * 512 + slot * 16 + (colbase & 7) * 2) = f2bf(v);
            }
        }
    }
    __syncthreads();   // zs written N-split, read across all cols

    // ---- phase C: head GEMM, N-split: wave w N-frags 5w..5w+4, K=256 ------
    const char* zb = (const char*)zs;
    const int p8 = l & 7;
    const int csrc = (l & 48) | (p8 ? (p8 - 1) : 0);

    f32x4 acc2[4][5];
    #pragma unroll
    for (int mm = 0; mm < 4; ++mm)
    #pragma unroll
    for (int nn = 0; nn < 5; ++nn) acc2[mm][nn] = (f32x4){0.f,0.f,0.f,0.f};

    #pragma unroll
    for (int kk = 0; kk < 8; ++kk) {
        short8 a[4];
        #pragma unroll
        for (int mm = 0; mm < 4; ++mm) {
            int row = mm * 16 + lr;
            a[mm] = *(const short8*)(zb + row * 512 + (((kk * 4 + lg) ^ (row & 7)) << 4));
        }
        const ushort* wp = WaP + ((size_t)kk * 20 + w * 5) * 512;
        #pragma unroll
        for (int nn = 0; nn < 5; ++nn) {
            short8 bq = *(const short8*)(wp + (size_t)nn * 512 + l * 8);
            acc2[0][nn] = __builtin_amdgcn_mfma_f32_16x16x32_bf16(a[0], bq, acc2[0][nn],0,0,0);
            acc2[1][nn] = __builtin_amdgcn_mfma_f32_16x16x32_bf16(a[1], bq, acc2[1][nn],0,0,0);
            acc2[2][nn] = __builtin_amdgcn_mfma_f32_16x16x32_bf16(a[2], bq, acc2[2][nn],0,0,0);
            acc2[3][nn] = __builtin_amdgcn_mfma_f32_16x16x32_bf16(a[3], bq, acc2[3][nn],0,0,0);
        }
    }

    // ---- phase E: bias, phase-weighted 8-lane reduce, store ---------------
    {
        float cw[4][4];
        #pragma unroll
        for (int mm = 0; mm < 4; ++mm)
        #pragma unroll
        for (int r = 0; r < 4; ++r)
            cw[mm][r] = __shfl(pwv[mm][r], csrc);

        #pragma unroll
        for (int nn = 0; nn < 5; ++nn) {
            int combo = (w * 5 + nn) * 16 + lr;
            float wb = wbias[combo];
            #pragma unroll
            for (int mm = 0; mm < 4; ++mm)
            #pragma unroll
            for (int r = 0; r < 4; ++r) {
                float e = acc2[mm][nn][r] + wb;
                float val = (p8 ? cw[mm][r] : 1.0f) * e;
                val += __shfl_xor(val, 1);
                val += __shfl_xor(val, 2);
                val += __shfl_xor(val, 4);
                if (p8 == 0) {
                    int h = combo / 160, rem = combo % 160, kb = rem >> 3;
                    size_t t = block0 + mm * 16 + lg * 4 + r;
                    out[(size_t)h * (BT * BINS) + t * BINS + kb] = val;
                }
            }
        }
    }
}

// ---------------------------------------------------------------------------
extern "C" void kernel_launch(void* const* d_in, const int* in_sizes, int n_in,
                              void* d_out, int out_size, void* d_ws, size_t ws_size,
                              hipStream_t stream) {
    const float* h_t          = (const float*)d_in[0];
    const float* a_t          = (const float*)d_in[1];
    const float* d_t          = (const float*)d_in[2];
    const float* age_embed    = (const float*)d_in[3];
    const float* trunk_w      = (const float*)d_in[4];
    const float* trunk_b      = (const float*)d_in[5];
    const float* inst_base_w  = (const float*)d_in[6];
    const float* inst_base_b  = (const float*)d_in[7];
    const float* group_base_w = (const float*)d_in[8];
    const float* group_base_b = (const float*)d_in[9];
    const float* inst_exp_w   = (const float*)d_in[10];
    const float* inst_exp_b   = (const float*)d_in[11];
    const float* group_exp_w  = (const float*)d_in[12];
    const float* group_exp_b  = (const float*)d_in[13];
    const float* router_w     = (const float*)d_in[14];
    const float* router_b     = (const float*)d_in[15];

    ushort* WtP   = (ushort*)d_ws;
    ushort* RP    = WtP + WT_P_SZ;
    ushort* WaP   = RP + RP_SZ;
    float*  wbias = (float*)(WaP + WA_P_SZ);

    pack_all<<<481, 64, 0, stream>>>(
        trunk_w, router_w,
        inst_base_w, inst_base_b, group_base_w, group_base_b,
        inst_exp_w, inst_exp_b, group_exp_w, group_exp_b,
        WtP, RP, WaP, wbias);

    fused_mfma<<<BT / 64, 256, 0, stream>>>(
        h_t, a_t, d_t, age_embed, trunk_b, router_b,
        WtP, RP, WaP, wbias, (float*)d_out);
}

// Round 7
// 103.029 us; speedup vs baseline: 1.0768x; 1.0768x over previous
//
#include <hip/hip_runtime.h>
#include <math.h>

typedef unsigned int uint;
typedef unsigned short ushort;

using short8 = __attribute__((ext_vector_type(8))) short;
using f32x4  = __attribute__((ext_vector_type(4))) float;

#define BT      65536
#define HID     512
#define IN_DIM  594
#define TRUNK   256
#define BINS    20
#define NCOMBO  320

#define WT_P_SZ (19*16*64*8)
#define RP_SZ   (16*64*8)
#define WA_P_SZ (8*20*64*8)

__device__ inline ushort f2bf(float f) {
    uint u = __float_as_uint(f);
    return (ushort)((u + 0x7fffu + ((u >> 16) & 1u)) >> 16);   // RNE
}

// ---------------------------------------------------------------------------
// Pack weights to bf16 MFMA B-fragment layout (verified R2-R6):
//   frag elem j, lane l, frag (kk,n): B[k][col], k=kk*32+(l>>4)*8+j, col=n*16+(l&15)
// ---------------------------------------------------------------------------
__global__ __launch_bounds__(64) void pack_all(
    const float* __restrict__ trunk_w, const float* __restrict__ router_w,
    const float* __restrict__ inst_base_w, const float* __restrict__ inst_base_b,
    const float* __restrict__ group_base_w, const float* __restrict__ group_base_b,
    const float* __restrict__ inst_exp_w, const float* __restrict__ inst_exp_b,
    const float* __restrict__ group_exp_w, const float* __restrict__ group_exp_b,
    ushort* __restrict__ WtP, ushort* __restrict__ RP,
    ushort* __restrict__ WaP, float* __restrict__ wbias)
{
    const int b = blockIdx.x, l = threadIdx.x;
    const int lr = l & 15, lg = l >> 4;
    if (b < 304) {                      // trunk: kk 0..18, n 0..15
        int kk = b >> 4, n = b & 15;
        int col = n * 16 + lr;
        ushort* dst = WtP + ((size_t)(kk * 16 + n) * 64 + l) * 8;
        #pragma unroll
        for (int j = 0; j < 8; ++j) {
            int k = kk * 32 + lg * 8 + j;
            dst[j] = (k < IN_DIM) ? f2bf(trunk_w[k * TRUNK + col]) : (ushort)0;
        }
    } else if (b < 320) {               // router: kk 0..15
        int kk = b - 304;
        ushort* dst = RP + ((size_t)(kk * 64 + l)) * 8;
        #pragma unroll
        for (int j = 0; j < 8; ++j) {
            int k = kk * 32 + lg * 8 + j;
            dst[j] = (lr < 7) ? f2bf(router_w[k * 7 + lr]) : (ushort)0;
        }
    } else if (b < 480) {               // heads: kk 0..7, n 0..19
        int b2 = b - 320, kk = b2 / 20, n = b2 % 20;
        int combo = n * 16 + lr;
        int h = combo / 160, rem = combo % 160, kb = rem >> 3, p = rem & 7;
        const float* bw = h ? group_base_w : inst_base_w;
        const float* ew = h ? group_exp_w  : inst_exp_w;
        ushort* dst = WaP + ((size_t)(kk * 20 + n) * 64 + l) * 8;
        #pragma unroll
        for (int j = 0; j < 8; ++j) {
            int k = kk * 32 + lg * 8 + j;
            float v = (p == 0) ? bw[k * BINS + kb]
                               : ew[((p - 1) * TRUNK + k) * BINS + kb];
            dst[j] = f2bf(v);
        }
    } else {                            // bias[320]
        for (int c = l; c < NCOMBO; c += 64) {
            int h = c / 160, rem = c % 160, kb = rem >> 3, p = rem & 7;
            const float* bb = h ? group_base_b : inst_base_b;
            const float* eb = h ? group_exp_b  : inst_exp_b;
            wbias[c] = (p == 0) ? bb[kb] : eb[(p - 1) * BINS + kb];
        }
    }
}

// ---------------------------------------------------------------------------
// Fused main (R5 base + phase-A K-pairing + phase-C N-split):
// 128 tokens/block, 4 waves, 512 blocks (2 blocks/CU).
// Phase A: N-split trunk (wave w: N-frags 4w..4w+3, all 8 M-frags), K-chunks
//          processed in PAIRS (BK=64): 10 barriers instead of 19, prefetch
//          gets ~2x MFMA cover. Staging keeps R5's bank-clean (srow,half) map.
// Phase C: N-split heads (wave w: N-frags 5w..5w+4, all 8 M-frags) -> head
//          weights read ONCE per block (160 KB vs 640 KB).
// pw shared across waves via pwl[128][9] (pad 9 -> conflict-free).
// LDS: zs[128][256] bf16 swizzled (64 KB); xs[2][2-chunk] overlaps first 32 KB.
// ---------------------------------------------------------------------------
__global__ __launch_bounds__(256, 2) void fused_mfma(
    const float* __restrict__ h_t, const float* __restrict__ a_t,
    const float* __restrict__ d_t, const float* __restrict__ age,
    const float* __restrict__ trunk_b, const float* __restrict__ router_b,
    const ushort* __restrict__ WtP, const ushort* __restrict__ RP,
    const ushort* __restrict__ WaP, const float* __restrict__ wbias,
    float* __restrict__ out)
{
    __shared__ alignas(16) ushort zs[32768];   // 64 KB; xs = first 16384 ushorts
    __shared__ float pwl[128 * 9];             // 4.5 KB phase-weight share

    const int tid = threadIdx.x;
    const int l = tid & 63, w = tid >> 6;
    const int lr = l & 15, lg = l >> 4;
    const int block0 = blockIdx.x * 128;

    // staging map (R5, bank-clean): thread -> (row, 16-col half of 32-col chunk)
    const int srow = tid >> 1;
    const int half = tid & 1;
    const size_t stok = block0 + srow;

    ushort* xs = zs;    // xs[buf][slot][frag mm][lane*8]; buf 8192, slot 4096 ushorts

    f32x4 acc[8][4];                          // [M-frag][N-frag]
    f32x4 accr0 = (f32x4){0.f,0.f,0.f,0.f};  // router, M-frag 2w   (rows w*32..)
    f32x4 accr1 = (f32x4){0.f,0.f,0.f,0.f};  // router, M-frag 2w+1
    #pragma unroll
    for (int mm = 0; mm < 8; ++mm)
    #pragma unroll
    for (int nn = 0; nn < 4; ++nn) acc[mm][nn] = (f32x4){0.f,0.f,0.f,0.f};

    auto stage_load_one = [&](int kk, float4* dst) {   // dst[4] = 16 floats
        if (kk < 16) {
            const float4* p = (const float4*)(h_t + stok * HID + kk * 32 + half * 16);
            dst[0]=p[0]; dst[1]=p[1]; dst[2]=p[2]; dst[3]=p[3];
        } else if (kk < 18) {
            const float4* p = (const float4*)(a_t + stok * 64 + (kk - 16) * 32 + half * 16);
            dst[0]=p[0]; dst[1]=p[1]; dst[2]=p[2]; dst[3]=p[3];
        } else {
            float* f = (float*)dst;
            #pragma unroll
            for (int j = 0; j < 16; ++j) {
                int c = 576 + half * 16 + j;
                float v;
                if (c < 578)      v = d_t[stok * 2 + (c - 576)];
                else if (c < 594) v = age[stok * 16 + (c - 578)];
                else              v = 0.f;
                f[j] = v;
            }
        }
    };
    auto stage_write_one = [&](int buf, int slot, const float4* ld) {
        const float* f = (const float*)ld;
        short8 v0, v1;
        #pragma unroll
        for (int j = 0; j < 8; ++j) {
            v0[j] = (short)f2bf(f[j]);
            v1[j] = (short)f2bf(f[j + 8]);
        }
        ushort* dst = xs + buf * 8192 + slot * 4096
                      + (srow >> 4) * 512 + ((srow & 15) + half * 32) * 8;
        *(short8*)dst = v0;
        *(short8*)(dst + 128) = v1;     // lane + 16
    };

    auto mfma_chunk = [&](const ushort* xb, int kk, bool do_router) {
        short8 a[8];
        #pragma unroll
        for (int mm = 0; mm < 8; ++mm)
            a[mm] = *(const short8*)(xb + (mm * 64 + l) * 8);
        if (do_router) {
            short8 rb  = *(const short8*)(RP + (size_t)kk * 512 + l * 8);
            short8 ar0 = *(const short8*)(xb + ((2 * w + 0) * 64 + l) * 8);
            short8 ar1 = *(const short8*)(xb + ((2 * w + 1) * 64 + l) * 8);
            accr0 = __builtin_amdgcn_mfma_f32_16x16x32_bf16(ar0, rb, accr0, 0, 0, 0);
            accr1 = __builtin_amdgcn_mfma_f32_16x16x32_bf16(ar1, rb, accr1, 0, 0, 0);
        }
        const ushort* wp = WtP + ((size_t)kk * 16 + w * 4) * 512;
        #pragma unroll
        for (int nn = 0; nn < 4; ++nn) {
            short8 bq = *(const short8*)(wp + (size_t)nn * 512 + l * 8);
            acc[0][nn] = __builtin_amdgcn_mfma_f32_16x16x32_bf16(a[0], bq, acc[0][nn],0,0,0);
            acc[1][nn] = __builtin_amdgcn_mfma_f32_16x16x32_bf16(a[1], bq, acc[1][nn],0,0,0);
            acc[2][nn] = __builtin_amdgcn_mfma_f32_16x16x32_bf16(a[2], bq, acc[2][nn],0,0,0);
            acc[3][nn] = __builtin_amdgcn_mfma_f32_16x16x32_bf16(a[3], bq, acc[3][nn],0,0,0);
            acc[4][nn] = __builtin_amdgcn_mfma_f32_16x16x32_bf16(a[4], bq, acc[4][nn],0,0,0);
            acc[5][nn] = __builtin_amdgcn_mfma_f32_16x16x32_bf16(a[5], bq, acc[5][nn],0,0,0);
            acc[6][nn] = __builtin_amdgcn_mfma_f32_16x16x32_bf16(a[6], bq, acc[6][nn],0,0,0);
            acc[7][nn] = __builtin_amdgcn_mfma_f32_16x16x32_bf16(a[7], bq, acc[7][nn],0,0,0);
        }
    };

    // ---- phase A: trunk (K=608) + router (K=512), paired chunks -----------
    {
        float4 ld[8];
        stage_load_one(0, ld);
        stage_load_one(1, ld + 4);
        stage_write_one(0, 0, ld);
        stage_write_one(0, 1, ld + 4);
        __syncthreads();
        int cur = 0;
        #pragma unroll 1
        for (int i = 0; i < 8; ++i) {        // pairs (0,1)..(14,15), prefetch next
            float4 nld[8];
            stage_load_one(2 * i + 2, nld);
            stage_load_one(2 * i + 3, nld + 4);
            const ushort* xb = xs + cur * 8192;
            mfma_chunk(xb,        2 * i,     true);
            mfma_chunk(xb + 4096, 2 * i + 1, true);
            stage_write_one(cur ^ 1, 0, nld);
            stage_write_one(cur ^ 1, 1, nld + 4);
            __syncthreads();
            cur ^= 1;
        }
        {   // pair (16,17) (no router), prefetch tail 18
            float4 tld[4];
            stage_load_one(18, tld);
            const ushort* xb = xs + cur * 8192;
            mfma_chunk(xb,        16, false);
            mfma_chunk(xb + 4096, 17, false);
            stage_write_one(cur ^ 1, 0, tld);
            __syncthreads();
            cur ^= 1;
        }
        mfma_chunk(xs + cur * 8192, 18, false);   // tail chunk
    }

    // ---- router softmax (rows w*32..+31) + share pw via LDS ---------------
    {
        const float rb_l = (lr < 7) ? router_b[lr] : 0.f;
        float pwv[2][4];
        #pragma unroll
        for (int m = 0; m < 2; ++m)
        #pragma unroll
        for (int r = 0; r < 4; ++r) {
            float lv = (m == 0) ? accr0[r] : accr1[r];
            float x = (lr < 7) ? (lv + rb_l) : -3.0e38f;
            float mx = x;
            mx = fmaxf(mx, __shfl_xor(mx, 1));
            mx = fmaxf(mx, __shfl_xor(mx, 2));
            mx = fmaxf(mx, __shfl_xor(mx, 4));
            mx = fmaxf(mx, __shfl_xor(mx, 8));
            float e = expf(x - mx);
            float s = e;
            s += __shfl_xor(s, 1);
            s += __shfl_xor(s, 2);
            s += __shfl_xor(s, 4);
            s += __shfl_xor(s, 8);
            pwv[m][r] = e / s;
        }
        if (lr < 7) {
            #pragma unroll
            for (int m = 0; m < 2; ++m)
            #pragma unroll
            for (int r = 0; r < 4; ++r)
                pwl[(w * 32 + m * 16 + lg * 4 + r) * 9 + lr] = pwv[m][r];
        }
    }

    // ---- epilogue: bias + exact GELU -> swizzled bf16 zs ------------------
    // wave w writes cols w*64..+63 for all 128 rows (xs region dead now)
    {
        char* zb = (char*)zs;
        #pragma unroll
        for (int nn = 0; nn < 4; ++nn) {
            int colbase = (w * 4 + nn) * 16 + lr;
            float tb = trunk_b[colbase];
            #pragma unroll
            for (int mm = 0; mm < 8; ++mm)
            #pragma unroll
            for (int r = 0; r < 4; ++r) {
                float v = acc[mm][nn][r] + tb;
                v = 0.5f * v * (1.f + erff(v * 0.70710678118654752f));
                int row  = mm * 16 + lg * 4 + r;
                int slot = (colbase >> 3) ^ (row & 7);
                *(ushort*)(zb + row * 512 + slot * 16 + (colbase & 7) * 2) = f2bf(v);
            }
        }
    }
    __syncthreads();   // zs + pwl cross-wave visibility

    // ---- phase C: head GEMM, N-split: wave w N-frags 5w..5w+4, K=256 ------
    const char* zb = (const char*)zs;
    const int p8 = l & 7;

    f32x4 acc2[8][5];
    #pragma unroll
    for (int mm = 0; mm < 8; ++mm)
    #pragma unroll
    for (int nn = 0; nn < 5; ++nn) acc2[mm][nn] = (f32x4){0.f,0.f,0.f,0.f};

    #pragma unroll
    for (int kk = 0; kk < 8; ++kk) {
        short8 a[8];
        #pragma unroll
        for (int mm = 0; mm < 8; ++mm) {
            int row = mm * 16 + lr;
            a[mm] = *(const short8*)(zb + row * 512 + (((kk * 4 + lg) ^ (row & 7)) << 4));
        }
        const ushort* wp = WaP + ((size_t)kk * 20 + w * 5) * 512;
        #pragma unroll
        for (int nn = 0; nn < 5; ++nn) {
            short8 bq = *(const short8*)(wp + (size_t)nn * 512 + l * 8);
            acc2[0][nn] = __builtin_amdgcn_mfma_f32_16x16x32_bf16(a[0], bq, acc2[0][nn],0,0,0);
            acc2[1][nn] = __builtin_amdgcn_mfma_f32_16x16x32_bf16(a[1], bq, acc2[1][nn],0,0,0);
            acc2[2][nn] = __builtin_amdgcn_mfma_f32_16x16x32_bf16(a[2], bq, acc2[2][nn],0,0,0);
            acc2[3][nn] = __builtin_amdgcn_mfma_f32_16x16x32_bf16(a[3], bq, acc2[3][nn],0,0,0);
            acc2[4][nn] = __builtin_amdgcn_mfma_f32_16x16x32_bf16(a[4], bq, acc2[4][nn],0,0,0);
            acc2[5][nn] = __builtin_amdgcn_mfma_f32_16x16x32_bf16(a[5], bq, acc2[5][nn],0,0,0);
            acc2[6][nn] = __builtin_amdgcn_mfma_f32_16x16x32_bf16(a[6], bq, acc2[6][nn],0,0,0);
            acc2[7][nn] = __builtin_amdgcn_mfma_f32_16x16x32_bf16(a[7], bq, acc2[7][nn],0,0,0);
        }
    }

    // ---- phase E: bias, phase-weighted 8-lane reduce, store ---------------
    {
        float cwv[8][4];
        const int psel = p8 ? (p8 - 1) : 0;
        #pragma unroll
        for (int mm = 0; mm < 8; ++mm)
        #pragma unroll
        for (int r = 0; r < 4; ++r)
            cwv[mm][r] = pwl[(mm * 16 + lg * 4 + r) * 9 + psel];

        #pragma unroll
        for (int nn = 0; nn < 5; ++nn) {
            int combo = (w * 5 + nn) * 16 + lr;
            float wb = wbias[combo];
            int h = combo / 160, rem = combo % 160, kb = rem >> 3;
            #pragma unroll
            for (int mm = 0; mm < 8; ++mm)
            #pragma unroll
            for (int r = 0; r < 4; ++r) {
                float e = acc2[mm][nn][r] + wb;
                float val = (p8 ? cwv[mm][r] : 1.0f) * e;
                val += __shfl_xor(val, 1);
                val += __shfl_xor(val, 2);
                val += __shfl_xor(val, 4);
                if (p8 == 0) {
                    size_t t = block0 + mm * 16 + lg * 4 + r;
                    out[(size_t)h * (BT * BINS) + t * BINS + kb] = val;
                }
            }
        }
    }
}

// ---------------------------------------------------------------------------
extern "C" void kernel_launch(void* const* d_in, const int* in_sizes, int n_in,
                              void* d_out, int out_size, void* d_ws, size_t ws_size,
                              hipStream_t stream) {
    const float* h_t          = (const float*)d_in[0];
    const float* a_t          = (const float*)d_in[1];
    const float* d_t          = (const float*)d_in[2];
    const float* age_embed    = (const float*)d_in[3];
    const float* trunk_w      = (const float*)d_in[4];
    const float* trunk_b      = (const float*)d_in[5];
    const float* inst_base_w  = (const float*)d_in[6];
    const float* inst_base_b  = (const float*)d_in[7];
    const float* group_base_w = (const float*)d_in[8];
    const float* group_base_b = (const float*)d_in[9];
    const float* inst_exp_w   = (const float*)d_in[10];
    const float* inst_exp_b   = (const float*)d_in[11];
    const float* group_exp_w  = (const float*)d_in[12];
    const float* group_exp_b  = (const float*)d_in[13];
    const float* router_w     = (const float*)d_in[14];
    const float* router_b     = (const float*)d_in[15];

    ushort* WtP   = (ushort*)d_ws;
    ushort* RP    = WtP + WT_P_SZ;
    ushort* WaP   = RP + RP_SZ;
    float*  wbias = (float*)(WaP + WA_P_SZ);

    pack_all<<<481, 64, 0, stream>>>(
        trunk_w, router_w,
        inst_base_w, inst_base_b, group_base_w, group_base_b,
        inst_exp_w, inst_exp_b, group_exp_w, group_exp_b,
        WtP, RP, WaP, wbias);

    fused_mfma<<<BT / 128, 256, 0, stream>>>(
        h_t, a_t, d_t, age_embed, trunk_b, router_b,
        WtP, RP, WaP, wbias, (float*)d_out);
}